// Round 8
// baseline (209.188 us; speedup 1.0000x reference)
//
#include <hip/hip_runtime.h>
#include <math.h>
#include <type_traits>

#define T_STEPS 2048
#define NU 512
#define NCH 8192            // B*U independent chains
#define CHB 16              // chains per block (512 blocks -> 2 waves/CU on all 256 CUs)
#define PF 7                // iterations (of 4 steps) prefetched ahead

typedef int i4 __attribute__((ext_vector_type(4)));
template<int N> using ic = std::integral_constant<int, N>;

// Round-8 thesis: rounds 5 & 7 (different structures) both plateau at
// ~6.2 B/cy per ACTIVE CU = ~64 cache lines in flight x ~700cy latency ->
// per-wave/per-CU memory concurrency cap, with 128 of 256 CUs idle.
// Fix: 512 blocks x 16 chains (lanes 0-15 active). 4x vmcnt queues chip-wide,
// half the bytes per CU. Pipeline structure (asm buffer loads, counted vmcnt,
// register ring, incremental rotation, no LDS/no lgkm) copied from round 7:
//   per iter: 8 loads (64B each, 1 line) + 4 stores; ring PF=7 -> 56 lines
//   in flight/wave; steady wait vmcnt(63) (sound: 72 ops issued after target;
//   6-bit cap guarantees retirement), tail ramps down.
__global__ __launch_bounds__(64, 1)
void reshopf_kernel(const float* __restrict__ Xr, const float* __restrict__ Xi,
                    const float* __restrict__ r0, const float* __restrict__ phi0,
                    const float* __restrict__ omegas,
                    float* __restrict__ zr, float* __restrict__ r_f,
                    float* __restrict__ phi_f)
{
    const int lane = threadIdx.x;
    if (lane >= CHB) return;                     // exec-mask: 16 active lanes
    const int g    = blockIdx.x * CHB + lane;
    const int u    = g & (NU - 1);

    const float INV2PI = 0.15915494309189533577f;

    // per-chain constants
    const float wo    = omegas[u];
    const float sig   = 1.0f / (1.0f + __expf(-wo));
    const float a_rev = (sig * 19.5f + 0.5f) * 0.01f;     // om*dt, revolutions
    const float Ca    = __builtin_amdgcn_cosf(a_rev);     // cos(om*dt)
    const float Sa    = __builtin_amdgcn_sinf(a_rev);     // sin(om*dt)

    float r        = r0[g];
    const float p0 = phi0[g];
    float s = __builtin_amdgcn_sinf(p0 * INV2PI);
    float c = __builtin_amdgcn_cosf(p0 * INV2PI);
    float acc = 0.0f;                                     // sum of eps (radians)

    // buffer SRDs (stride 0, raw, bounds check disabled; exec handles masking)
    auto mksrd = [](const void* p) -> i4 {
        i4 v;
        v.x = (int)(unsigned)(uintptr_t)p;
        v.y = (int)((unsigned)((uintptr_t)p >> 32) & 0xFFFFu);
        v.z = (int)0xFFFFFFFFu;
        v.w = 0x00020000;
        return v;
    };
    const i4 srdR = mksrd(Xr), srdI = mksrd(Xi), srdZ = mksrd(zr);
    const unsigned voff = (unsigned)g * 4u;               // lane byte offset in a row

    float rgR[PF][4], rgI[PF][4];                          // register ring (static idx only)

    auto load1 = [&](float& dst, const i4& srd, unsigned soff) {
        asm volatile("buffer_load_dword %0, %1, %2, %3 offen"
                     : "=v"(dst) : "v"(voff), "s"(srd), "s"(soff));
    };
    auto loadgrp = [&](auto Pc, int i) {                   // stage iter i's 4 rows into slot P
        constexpr int P = decltype(Pc)::value;
        const unsigned b = (unsigned)i * 131072u;          // i*4 rows * 32768 B/row
        load1(rgR[P][0], srdR, b);
        load1(rgI[P][0], srdI, b);
        load1(rgR[P][1], srdR, b + 32768u);
        load1(rgI[P][1], srdI, b + 32768u);
        load1(rgR[P][2], srdR, b + 65536u);
        load1(rgI[P][2], srdI, b + 65536u);
        load1(rgR[P][3], srdR, b + 98304u);
        load1(rgI[P][3], srdI, b + 98304u);
    };
    auto store1 = [&](float zv, unsigned soff) {
        asm volatile("buffer_store_dword %0, %1, %2, %3 offen"
                     :: "v"(zv), "v"(voff), "s"(srdZ), "s"(soff) : "memory");
    };

    auto step = [&](float xr, float xi, unsigned soff) {
        const float kxi = xi * -0.05f;                     // off-chain
        const float kxr = xr * 0.05f;                      // off-chain
        const float eps = kxi * s;                         // -5*xi*sin(phi)*dt, radians
        const float t1  = s * Ca;
        const float sA  = fmaf(c, Sa, t1);                 // sin(phi+a)
        const float t2  = c * Ca;
        const float cA  = fmaf(-s, Sa, t2);                // cos(phi+a)
        const float rr  = r * r;
        const float g1  = fmaf(-rr, r, r);                 // (1-r^2)*r
        const float tr  = fmaf(kxr, c, r);                 // uses OLD cos(phi)
        r = fmaf(0.01f, g1, tr);
        s = fmaf(eps, cA, sA);                             // first-order rot(eps)
        c = fmaf(-eps, sA, cA);
        acc += eps;
        store1(r * c, soff);                               // Re(z) = r_new*cos(phi_new)
    };

    auto iter = [&](auto Pc, auto NWc, auto RFc, int i) {
        asm volatile("s_waitcnt vmcnt(%0)" :: "n"(decltype(NWc)::value) : "memory");
        __builtin_amdgcn_sched_barrier(0);                 // ring reads stay after wait
        constexpr int P = decltype(Pc)::value;
        const unsigned sb = (unsigned)i * 131072u;
        step(rgR[P][0], rgI[P][0], sb);
        step(rgR[P][1], rgI[P][1], sb + 32768u);
        step(rgR[P][2], rgI[P][2], sb + 65536u);
        step(rgR[P][3], rgI[P][3], sb + 98304u);
        // norm correction once per 4 steps (drift ~(1+eps^2) per step)
        const float m = fmaf(s, s, c * c);
        const float n = fmaf(-0.5f, m, 1.5f);
        s *= n; c *= n;
        if constexpr (decltype(RFc)::value) loadgrp(Pc, i + PF);  // refill AFTER consume
    };

    // prologue: 7 slots = 56 loads in flight
    loadgrp(ic<0>{}, 0); loadgrp(ic<1>{}, 1); loadgrp(ic<2>{}, 2);
    loadgrp(ic<3>{}, 3); loadgrp(ic<4>{}, 4); loadgrp(ic<5>{}, 5);
    loadgrp(ic<6>{}, 6);

    // first block: waits ramp 48,52,56,60 then 63 (sound: N <= ops-after-target)
    iter(ic<0>{}, ic<48>{}, ic<1>{}, 0);
    iter(ic<1>{}, ic<52>{}, ic<1>{}, 1);
    iter(ic<2>{}, ic<56>{}, ic<1>{}, 2);
    iter(ic<3>{}, ic<60>{}, ic<1>{}, 3);
    iter(ic<4>{}, ic<63>{}, ic<1>{}, 4);
    iter(ic<5>{}, ic<63>{}, ic<1>{}, 5);
    iter(ic<6>{}, ic<63>{}, ic<1>{}, 6);

    // steady state: iters 7..503 (71 blocks of 7), uniform vmcnt(63)
    for (int blk = 1; blk < 72; ++blk) {
        const int ib = blk * PF;
        iter(ic<0>{}, ic<63>{}, ic<1>{}, ib + 0);
        iter(ic<1>{}, ic<63>{}, ic<1>{}, ib + 1);
        iter(ic<2>{}, ic<63>{}, ic<1>{}, ib + 2);
        iter(ic<3>{}, ic<63>{}, ic<1>{}, ib + 3);
        iter(ic<4>{}, ic<63>{}, ic<1>{}, ib + 4);
        iter(ic<5>{}, ic<63>{}, ic<1>{}, ib + 5);
        iter(ic<6>{}, ic<63>{}, ic<1>{}, ib + 6);
    }
    // iter 504: last refill (grp 511 -> slot 0)
    iter(ic<0>{}, ic<63>{}, ic<1>{}, 504);

    // tail 505..511: no refills; waits ramp down (derived: 63,63,56,48,40,32,24)
    iter(ic<1>{}, ic<63>{}, ic<0>{}, 505);
    iter(ic<2>{}, ic<63>{}, ic<0>{}, 506);
    iter(ic<3>{}, ic<56>{}, ic<0>{}, 507);
    iter(ic<4>{}, ic<48>{}, ic<0>{}, 508);
    iter(ic<5>{}, ic<40>{}, ic<0>{}, 509);
    iter(ic<6>{}, ic<32>{}, ic<0>{}, 510);
    iter(ic<0>{}, ic<24>{}, ic<0>{}, 511);

    r_f[g] = r;
    // phi_f = p0 + 2048*a + sum(eps), widened to f64 at the end
    phi_f[g] = (float)((double)p0
                       + (double)a_rev * 2048.0 * 6.283185307179586476925287
                       + (double)acc);
}

extern "C" void kernel_launch(void* const* d_in, const int* in_sizes, int n_in,
                              void* d_out, int out_size, void* d_ws, size_t ws_size,
                              hipStream_t stream) {
    const float* Xr   = (const float*)d_in[0];
    const float* Xi   = (const float*)d_in[1];
    const float* r0   = (const float*)d_in[2];
    const float* phi0 = (const float*)d_in[3];
    const float* om   = (const float*)d_in[4];

    float* out   = (float*)d_out;
    float* zrp   = out;                               // Re(z): T*NCH floats
    float* r_f   = out + (size_t)T_STEPS * NCH;       // NCH floats
    float* phi_f = r_f + NCH;                         // NCH floats

    reshopf_kernel<<<NCH / CHB, 64, 0, stream>>>(Xr, Xi, r0, phi0, om, zrp, r_f, phi_f);
}

// Round 9
// 103.248 us; speedup vs baseline: 2.0261x; 2.0261x over previous
//
#include <hip/hip_runtime.h>
#include <math.h>

#define NU 512
#define NCH 8192
#define CPB 32              // chains per block
#define NBLK 256            // 256 blocks -> 1 per CU (96KB LDS forces it)

typedef int i4 __attribute__((ext_vector_type(4)));
typedef float f2 __attribute__((ext_vector_type(2)));

// Wave-specialized producer/consumer:
//   waves 0-3 (LSU): ALL global memory. inputs HBM->reg->LDS ring, z LDS->HBM.
//   wave 4 (compute): pure VALU + DS. zero global vmem in the hot loop.
// Rationale (R7/R8 post-mortem): per-wave 64-op in-order vmem queue shared by
// slow-retiring stores caps total in-flight bytes at ~2MB chip-wide for any
// single-wave-per-chain-group design. Specialization multiplies queues and
// removes store head-of-line blocking from the load path.
// Rings: in[2 arrays][64 slots][4 rows][32 ch] = 64KB, z[64][4][32] = 32KB.
// Phase = 32 iters (128 steps). 16 phases + 2 prologue barriers = 18 barriers,
// executed identically by all 5 waves (no conditional barriers).
// Slot(it) = it & 63; half parity = p&1. Loads for half h issued at phase
// h-2, LDS-written at h-1, consumed at h: every load ages >= 1 full phase
// (~4800 cy) before its vmcnt(0) -> tolerates L up to ~2 phases.
__device__ __forceinline__ i4 mksrd(const void* p) {
    i4 v;
    v.x = (int)(unsigned)(uintptr_t)p;
    v.y = (int)((unsigned)((uintptr_t)p >> 32) & 0xFFFFu);
    v.z = (int)0xFFFFFFFFu;        // bounds check off
    v.w = 0x00020000;              // raw dword SRD
    return v;
}

__global__ __launch_bounds__(320, 1)
void reshopf_kernel(const float* __restrict__ Xr, const float* __restrict__ Xi,
                    const float* __restrict__ r0, const float* __restrict__ phi0,
                    const float* __restrict__ omegas,
                    float* __restrict__ zr, float* __restrict__ r_f,
                    float* __restrict__ phi_f)
{
    __shared__ float lds[24576];   // [R in: 0..32KB) [I in: 32..64KB) [z: 64..96KB)
    const int tid   = (int)threadIdx.x;
    const int lane  = tid & 63;
    const int wid   = __builtin_amdgcn_readfirstlane(tid >> 6);   // 0..4, uniform
    const int cbase = (int)blockIdx.x * CPB;
    const unsigned ldsb = (unsigned)(uintptr_t)&lds[0];

    if (wid < 4) {
        // ===================== LSU waves =====================
        // one vmem op = 2 rows x 32 chains = 256B line-exact:
        //   lane -> row (lane>>5), chain (lane&31)
        const unsigned voff = ((unsigned)(lane >> 5)) * 32768u
                            + ((unsigned)(lane & 31)) * 4u;
        const i4 srdR = mksrd(Xr + cbase);
        const i4 srdI = mksrd(Xi + cbase);
        const i4 srdZ = mksrd(zr + cbase);
        // per-wave LDS base: slot = half*32 + wid*8 + il
        const unsigned wl = ldsb + (unsigned)wid * 4096u
                          + ((unsigned)(lane >> 5)) * 128u
                          + ((unsigned)(lane & 31)) * 4u;
        const int itw = wid * 8;            // this wave's iter stripe offset

        float pR[8][2], pI[8][2], zv[8][2]; // static-indexed (rule #20)

#define LD1(dst, srd, so) asm volatile("buffer_load_dword %0, %1, %2, %3 offen" \
        : "=v"(dst) : "v"(voff), "s"(srd), "s"(so))
#define LDIT(IL, base) { const unsigned s0_ = (unsigned)((base) + itw + IL) * 131072u; \
        LD1(pR[IL][0], srdR, s0_); LD1(pR[IL][1], srdR, s0_ + 65536u); \
        LD1(pI[IL][0], srdI, s0_); LD1(pI[IL][1], srdI, s0_ + 65536u); }
#define LOADS8(base) { LDIT(0, base) LDIT(1, base) LDIT(2, base) LDIT(3, base) \
                       LDIT(4, base) LDIT(5, base) LDIT(6, base) LDIT(7, base) }

#define WR1(val, ad, IMM) asm volatile("ds_write_b32 %0, %1 offset:%2" \
        :: "v"(ad), "v"(val), "n"(IMM))
#define WRIT(IL, WA) { WR1(pR[IL][0], WA, IL*512); WR1(pR[IL][1], WA, IL*512+256); \
        WR1(pI[IL][0], WA, 32768+IL*512); WR1(pI[IL][1], WA, 32768+IL*512+256); }
#define WRITES8(WA) { WRIT(0, WA) WRIT(1, WA) WRIT(2, WA) WRIT(3, WA) \
                      WRIT(4, WA) WRIT(5, WA) WRIT(6, WA) WRIT(7, WA) }

#define ZR1(dst, ad, IMM) asm volatile("ds_read_b32 %0, %1 offset:%2" \
        : "=v"(dst) : "v"(ad), "n"(IMM))
#define ZRIT(IL, ZA) { ZR1(zv[IL][0], ZA, IL*512); ZR1(zv[IL][1], ZA, IL*512+256); }
#define ZREADS8(ZA) { ZRIT(0, ZA) ZRIT(1, ZA) ZRIT(2, ZA) ZRIT(3, ZA) \
                      ZRIT(4, ZA) ZRIT(5, ZA) ZRIT(6, ZA) ZRIT(7, ZA) }

#define ZS1(val, so) asm volatile("buffer_store_dword %0, %1, %2, %3 offen" \
        :: "v"(val), "v"(voff), "s"(srdZ), "s"(so) : "memory")
#define ZSIT(IL, zb) { const unsigned s0_ = (unsigned)((zb) + itw + IL) * 131072u; \
        ZS1(zv[IL][0], s0_); ZS1(zv[IL][1], s0_ + 65536u); }
#define ZSTORES8(zb) { ZSIT(0, zb) ZSIT(1, zb) ZSIT(2, zb) ZSIT(3, zb) \
                       ZSIT(4, zb) ZSIT(5, zb) ZSIT(6, zb) ZSIT(7, zb) }

        // P(-2): issue loads half0
        LOADS8(0);
        __builtin_amdgcn_s_barrier();                              // #1
        // P(-1): write half0 (one-time ~L stall = pipe fill), issue half1
        asm volatile("s_waitcnt vmcnt(0)" ::: "memory");
        { const unsigned wa = wl; WRITES8(wa); }
        LOADS8(32);
        asm volatile("s_waitcnt lgkmcnt(0)" ::: "memory");
        __builtin_amdgcn_s_barrier();                              // #2

        for (int p = 0; p < 16; ++p) {
            const unsigned hp = ((unsigned)((p + 1) & 1)) * 16384u;
            asm volatile("s_waitcnt vmcnt(0)" ::: "memory");       // ops >=1 phase old
            if (p <= 14) { const unsigned wa = wl + hp; WRITES8(wa); }
            if (p >= 1) {
                const unsigned za = wl + 65536u + hp;              // z of half p-1 (same parity)
                ZREADS8(za);
                asm volatile("s_waitcnt lgkmcnt(0)" ::: "memory");
                ZSTORES8((p - 1) * 32);
            }
            if (p <= 13) LOADS8((p + 2) * 32);
            asm volatile("s_waitcnt lgkmcnt(0)" ::: "memory");
            __builtin_amdgcn_s_barrier();                          // #3..#18
        }
        // post: z of half 15 (parity 1)
        { const unsigned za = wl + 65536u + 16384u; ZREADS8(za); }
        asm volatile("s_waitcnt lgkmcnt(0)" ::: "memory");
        ZSTORES8(480);
    } else {
        // ===================== compute wave =====================
        const int l   = lane & 31;            // lanes 32-63 duplicate 0-31 (stores masked)
        const int gch = cbase + l;
        const float INV2PI = 0.15915494309189533577f;

        const float wo    = omegas[gch & (NU - 1)];
        const float sig   = 1.0f / (1.0f + __expf(-wo));
        const float a_rev = (sig * 19.5f + 0.5f) * 0.01f;
        const float Ca    = __builtin_amdgcn_cosf(a_rev);
        const float Sa    = __builtin_amdgcn_sinf(a_rev);

        float r        = r0[gch];
        const float p0 = phi0[gch];
        float s = __builtin_amdgcn_sinf(p0 * INV2PI);
        float c = __builtin_amdgcn_cosf(p0 * INV2PI);
        float acc = 0.0f;

        const unsigned vR = ldsb + (unsigned)l * 4u;
        const unsigned vI = vR + 32768u;
        const unsigned vZ = vR + 65536u;

        auto step = [&](float xr, float xi, float& zout) {
            const float kxi = xi * -0.05f;
            const float kxr = xr * 0.05f;
            const float eps = kxi * s;
            const float t1  = s * Ca;
            const float sA  = fmaf(c, Sa, t1);
            const float t2  = c * Ca;
            const float cA  = fmaf(-s, Sa, t2);
            const float rr  = r * r;
            const float g1  = fmaf(-rr, r, r);
            const float tr  = fmaf(kxr, c, r);
            r = fmaf(0.01f, g1, tr);
            s = fmaf(eps, cA, sA);
            c = fmaf(-eps, sA, cA);
            acc += eps;
            zout = r * c;
        };

#define RD(it, R01, R23, I01, I23) { \
        const unsigned so_ = ((unsigned)((it) & 63)) * 512u; \
        const unsigned aR_ = vR + so_, aI_ = vI + so_; \
        asm volatile("ds_read2_b32 %0, %1 offset0:0 offset1:32"  : "=v"(R01) : "v"(aR_)); \
        asm volatile("ds_read2_b32 %0, %1 offset0:64 offset1:96" : "=v"(R23) : "v"(aR_)); \
        asm volatile("ds_read2_b32 %0, %1 offset0:0 offset1:32"  : "=v"(I01) : "v"(aI_)); \
        asm volatile("ds_read2_b32 %0, %1 offset0:64 offset1:96" : "=v"(I23) : "v"(aI_)); }

#define COMP(it, R01, R23, I01, I23) { \
        float z0_, z1_, z2_, z3_; \
        step(R01.x, I01.x, z0_); step(R01.y, I01.y, z1_); \
        step(R23.x, I23.x, z2_); step(R23.y, I23.y, z3_); \
        const float m_ = fmaf(s, s, c * c); \
        const float n_ = fmaf(-0.5f, m_, 1.5f); \
        s *= n_; c *= n_; \
        const unsigned aZ_ = vZ + ((unsigned)((it) & 63)) * 512u; \
        asm volatile("ds_write2_b32 %0, %1, %2 offset0:0 offset1:32"  :: "v"(aZ_), "v"(z0_), "v"(z1_)); \
        asm volatile("ds_write2_b32 %0, %1, %2 offset0:64 offset1:96" :: "v"(aZ_), "v"(z2_), "v"(z3_)); }

#define W4 { asm volatile("s_waitcnt lgkmcnt(4)" ::: "memory"); __builtin_amdgcn_sched_barrier(0); }
#define W0 { asm volatile("s_waitcnt lgkmcnt(0)" ::: "memory"); __builtin_amdgcn_sched_barrier(0); }

        __builtin_amdgcn_s_barrier();                              // #1
        __builtin_amdgcn_s_barrier();                              // #2  (half0 sealed)

        f2 Ar01, Ar23, Ai01, Ai23, Br01, Br23, Bi01, Bi23;
        for (int p = 0; p < 16; ++p) {
            const int it0 = p * 32;
            RD(it0, Ar01, Ar23, Ai01, Ai23);
            for (int j = 0; j < 15; ++j) {
                const int k = it0 + 2 * j;
                RD(k + 1, Br01, Br23, Bi01, Bi23); W4; COMP(k,     Ar01, Ar23, Ai01, Ai23);
                RD(k + 2, Ar01, Ar23, Ai01, Ai23); W4; COMP(k + 1, Br01, Br23, Bi01, Bi23);
            }
            RD(it0 + 31, Br01, Br23, Bi01, Bi23); W4; COMP(it0 + 30, Ar01, Ar23, Ai01, Ai23);
            W0; COMP(it0 + 31, Br01, Br23, Bi01, Bi23);
            asm volatile("s_waitcnt lgkmcnt(0)" ::: "memory");     // z writes sealed
            __builtin_amdgcn_s_barrier();                          // #3..#18
        }

        if (lane < 32) {
            r_f[gch] = r;
            phi_f[gch] = (float)((double)p0
                         + (double)a_rev * 2048.0 * 6.283185307179586476925287
                         + (double)acc);
        }
    }
}

extern "C" void kernel_launch(void* const* d_in, const int* in_sizes, int n_in,
                              void* d_out, int out_size, void* d_ws, size_t ws_size,
                              hipStream_t stream) {
    const float* Xr   = (const float*)d_in[0];
    const float* Xi   = (const float*)d_in[1];
    const float* r0   = (const float*)d_in[2];
    const float* phi0 = (const float*)d_in[3];
    const float* om   = (const float*)d_in[4];

    float* out   = (float*)d_out;
    float* zrp   = out;                               // Re(z): T*NCH floats
    float* r_f   = out + (size_t)2048 * NCH;          // NCH floats
    float* phi_f = r_f + NCH;                         // NCH floats

    reshopf_kernel<<<NBLK, 320, 0, stream>>>(Xr, Xi, r0, phi0, om, zrp, r_f, phi_f);
}

// Round 10
// 101.992 us; speedup vs baseline: 2.0510x; 1.0123x over previous
//
#include <hip/hip_runtime.h>
#include <math.h>

#define NU 512
#define NCH 8192
#define CPB 32              // chains per block
#define NBLK 256            // 1 block/CU (96KB LDS)

typedef int i4 __attribute__((ext_vector_type(4)));
typedef float f2 __attribute__((ext_vector_type(2)));
typedef float f4 __attribute__((ext_vector_type(4)));

// R10 = R9 skeleton (proven correct, absmax 8.0) with LSU waves converted from
// dword (256B/inst) to dwordx4 (1KB/inst) ops. Theory: all four prior
// structures plateau at ~1.3 TB/s because vmem INSTRUCTION throughput
// (~40cy/inst/CU through TCP under miss traffic) binds, not bytes.
// dwordx4: lane l -> row (l>>3), chains 4*(l&7): one inst = 8 rows x 32 ch.
// Per LSU wave per phase: 8 loads + 4 ds_write_b128 + 4 ds_read_b128 +
// 4 stores (was 32+32+16+16). Compute wave, barriers, LDS byte layout,
// parity schedule: IDENTICAL to R9.
__device__ __forceinline__ i4 mksrd(const void* p) {
    i4 v;
    v.x = (int)(unsigned)(uintptr_t)p;
    v.y = (int)((unsigned)((uintptr_t)p >> 32) & 0xFFFFu);
    v.z = (int)0xFFFFFFFFu;        // bounds check off
    v.w = 0x00020000;              // raw dword SRD
    return v;
}

__global__ __launch_bounds__(320, 1)
void reshopf_kernel(const float* __restrict__ Xr, const float* __restrict__ Xi,
                    const float* __restrict__ r0, const float* __restrict__ phi0,
                    const float* __restrict__ omegas,
                    float* __restrict__ zr, float* __restrict__ r_f,
                    float* __restrict__ phi_f)
{
    __shared__ float lds[24576];   // [R in: 0..32KB) [I in: 32..64KB) [z: 64..96KB)
    const int tid   = (int)threadIdx.x;
    const int lane  = tid & 63;
    const int wid   = __builtin_amdgcn_readfirstlane(tid >> 6);   // 0..4, uniform
    const int cbase = (int)blockIdx.x * CPB;
    const unsigned ldsb = (unsigned)(uintptr_t)&lds[0];

    if (wid < 4) {
        // ===================== LSU waves (dwordx4) =====================
        // lane l: row = l>>3 (8 rows/inst), chains 4*(l&7) (16B)
        const unsigned voff = ((unsigned)(lane >> 3)) * 32768u
                            + ((unsigned)(lane & 7)) * 16u;
        const i4 srdR = mksrd(Xr + cbase);
        const i4 srdI = mksrd(Xi + cbase);
        const i4 srdZ = mksrd(zr + cbase);
        // per-lane LDS base inside this wave's 32-row stripe (w*32 rows = 4KB)
        const unsigned wl = ldsb + (unsigned)wid * 4096u
                          + ((unsigned)(lane >> 3)) * 128u
                          + ((unsigned)(lane & 7)) * 16u;

        f4 pR[4], pI[4], zv[4];    // static-indexed only

#define LD4(dst, srd, so) asm volatile("buffer_load_dwordx4 %0, %1, %2, %3 offen" \
        : "=v"(dst) : "v"(voff), "s"(srd), "s"(so))
#define LOADS(baseRow) { \
        const unsigned s0_ = ((unsigned)(baseRow) + (unsigned)wid * 32u) * 32768u; \
        LD4(pR[0], srdR, s0_);            LD4(pR[1], srdR, s0_ + 262144u); \
        LD4(pR[2], srdR, s0_ + 524288u);  LD4(pR[3], srdR, s0_ + 786432u); \
        LD4(pI[0], srdI, s0_);            LD4(pI[1], srdI, s0_ + 262144u); \
        LD4(pI[2], srdI, s0_ + 524288u);  LD4(pI[3], srdI, s0_ + 786432u); }

#define WRITES(HP) { const unsigned a_ = wl + (HP); \
        asm volatile("ds_write_b128 %0, %1 offset:0"     :: "v"(a_), "v"(pR[0])); \
        asm volatile("ds_write_b128 %0, %1 offset:1024"  :: "v"(a_), "v"(pR[1])); \
        asm volatile("ds_write_b128 %0, %1 offset:2048"  :: "v"(a_), "v"(pR[2])); \
        asm volatile("ds_write_b128 %0, %1 offset:3072"  :: "v"(a_), "v"(pR[3])); \
        asm volatile("ds_write_b128 %0, %1 offset:32768" :: "v"(a_), "v"(pI[0])); \
        asm volatile("ds_write_b128 %0, %1 offset:33792" :: "v"(a_), "v"(pI[1])); \
        asm volatile("ds_write_b128 %0, %1 offset:34816" :: "v"(a_), "v"(pI[2])); \
        asm volatile("ds_write_b128 %0, %1 offset:35840" :: "v"(a_), "v"(pI[3])); }

#define ZREADS(HP) { const unsigned a_ = wl + 65536u + (HP); \
        asm volatile("ds_read_b128 %0, %1 offset:0"    : "=v"(zv[0]) : "v"(a_)); \
        asm volatile("ds_read_b128 %0, %1 offset:1024" : "=v"(zv[1]) : "v"(a_)); \
        asm volatile("ds_read_b128 %0, %1 offset:2048" : "=v"(zv[2]) : "v"(a_)); \
        asm volatile("ds_read_b128 %0, %1 offset:3072" : "=v"(zv[3]) : "v"(a_)); }

#define ZSTORES(baseRow) { \
        const unsigned s0_ = ((unsigned)(baseRow) + (unsigned)wid * 32u) * 32768u; \
        asm volatile("buffer_store_dwordx4 %0, %1, %2, %3 offen" \
            :: "v"(zv[0]), "v"(voff), "s"(srdZ), "s"(s0_) : "memory"); \
        asm volatile("buffer_store_dwordx4 %0, %1, %2, %3 offen" \
            :: "v"(zv[1]), "v"(voff), "s"(srdZ), "s"(s0_ + 262144u) : "memory"); \
        asm volatile("buffer_store_dwordx4 %0, %1, %2, %3 offen" \
            :: "v"(zv[2]), "v"(voff), "s"(srdZ), "s"(s0_ + 524288u) : "memory"); \
        asm volatile("buffer_store_dwordx4 %0, %1, %2, %3 offen" \
            :: "v"(zv[3]), "v"(voff), "s"(srdZ), "s"(s0_ + 786432u) : "memory"); }

        // P(-2): issue loads half0 (rows 0..127)
        LOADS(0);
        __builtin_amdgcn_s_barrier();                              // #1
        // P(-1): write half0 (one-time pipe-fill stall), issue half1
        asm volatile("s_waitcnt vmcnt(0)" ::: "memory");
        WRITES(0u);
        LOADS(128);
        asm volatile("s_waitcnt lgkmcnt(0)" ::: "memory");
        __builtin_amdgcn_s_barrier();                              // #2

        for (int p = 0; p < 16; ++p) {
            const unsigned hp = ((unsigned)((p + 1) & 1)) * 16384u;
            asm volatile("s_waitcnt vmcnt(0)" ::: "memory");       // ops >=1 phase old
            if (p <= 14) WRITES(hp);
            if (p >= 1) {
                ZREADS(hp);                                        // z of phase p-1
                asm volatile("s_waitcnt lgkmcnt(0)" ::: "memory");
                ZSTORES((p - 1) * 128);
            }
            if (p <= 13) LOADS((p + 2) * 128);
            asm volatile("s_waitcnt lgkmcnt(0)" ::: "memory");
            __builtin_amdgcn_s_barrier();                          // #3..#18
        }
        // post: z of phase 15 (parity 1)
        ZREADS(16384u);
        asm volatile("s_waitcnt lgkmcnt(0)" ::: "memory");
        ZSTORES(1920);
    } else {
        // ===================== compute wave (verbatim R9) =====================
        const int l   = lane & 31;            // lanes 32-63 duplicate 0-31
        const int gch = cbase + l;
        const float INV2PI = 0.15915494309189533577f;

        const float wo    = omegas[gch & (NU - 1)];
        const float sig   = 1.0f / (1.0f + __expf(-wo));
        const float a_rev = (sig * 19.5f + 0.5f) * 0.01f;
        const float Ca    = __builtin_amdgcn_cosf(a_rev);
        const float Sa    = __builtin_amdgcn_sinf(a_rev);

        float r        = r0[gch];
        const float p0 = phi0[gch];
        float s = __builtin_amdgcn_sinf(p0 * INV2PI);
        float c = __builtin_amdgcn_cosf(p0 * INV2PI);
        float acc = 0.0f;

        const unsigned vR = ldsb + (unsigned)l * 4u;
        const unsigned vI = vR + 32768u;
        const unsigned vZ = vR + 65536u;

        auto step = [&](float xr, float xi, float& zout) {
            const float kxi = xi * -0.05f;
            const float kxr = xr * 0.05f;
            const float eps = kxi * s;
            const float t1  = s * Ca;
            const float sA  = fmaf(c, Sa, t1);
            const float t2  = c * Ca;
            const float cA  = fmaf(-s, Sa, t2);
            const float rr  = r * r;
            const float g1  = fmaf(-rr, r, r);
            const float tr  = fmaf(kxr, c, r);
            r = fmaf(0.01f, g1, tr);
            s = fmaf(eps, cA, sA);
            c = fmaf(-eps, sA, cA);
            acc += eps;
            zout = r * c;
        };

#define RD(it, R01, R23, I01, I23) { \
        const unsigned so_ = ((unsigned)((it) & 63)) * 512u; \
        const unsigned aR_ = vR + so_, aI_ = vI + so_; \
        asm volatile("ds_read2_b32 %0, %1 offset0:0 offset1:32"  : "=v"(R01) : "v"(aR_)); \
        asm volatile("ds_read2_b32 %0, %1 offset0:64 offset1:96" : "=v"(R23) : "v"(aR_)); \
        asm volatile("ds_read2_b32 %0, %1 offset0:0 offset1:32"  : "=v"(I01) : "v"(aI_)); \
        asm volatile("ds_read2_b32 %0, %1 offset0:64 offset1:96" : "=v"(I23) : "v"(aI_)); }

#define COMP(it, R01, R23, I01, I23) { \
        float z0_, z1_, z2_, z3_; \
        step(R01.x, I01.x, z0_); step(R01.y, I01.y, z1_); \
        step(R23.x, I23.x, z2_); step(R23.y, I23.y, z3_); \
        const float m_ = fmaf(s, s, c * c); \
        const float n_ = fmaf(-0.5f, m_, 1.5f); \
        s *= n_; c *= n_; \
        const unsigned aZ_ = vZ + ((unsigned)((it) & 63)) * 512u; \
        asm volatile("ds_write2_b32 %0, %1, %2 offset0:0 offset1:32"  :: "v"(aZ_), "v"(z0_), "v"(z1_)); \
        asm volatile("ds_write2_b32 %0, %1, %2 offset0:64 offset1:96" :: "v"(aZ_), "v"(z2_), "v"(z3_)); }

#define W4 { asm volatile("s_waitcnt lgkmcnt(4)" ::: "memory"); __builtin_amdgcn_sched_barrier(0); }
#define W0 { asm volatile("s_waitcnt lgkmcnt(0)" ::: "memory"); __builtin_amdgcn_sched_barrier(0); }

        __builtin_amdgcn_s_barrier();                              // #1
        __builtin_amdgcn_s_barrier();                              // #2  (half0 sealed)

        f2 Ar01, Ar23, Ai01, Ai23, Br01, Br23, Bi01, Bi23;
        for (int p = 0; p < 16; ++p) {
            const int it0 = p * 32;
            RD(it0, Ar01, Ar23, Ai01, Ai23);
            for (int j = 0; j < 15; ++j) {
                const int k = it0 + 2 * j;
                RD(k + 1, Br01, Br23, Bi01, Bi23); W4; COMP(k,     Ar01, Ar23, Ai01, Ai23);
                RD(k + 2, Ar01, Ar23, Ai01, Ai23); W4; COMP(k + 1, Br01, Br23, Bi01, Bi23);
            }
            RD(it0 + 31, Br01, Br23, Bi01, Bi23); W4; COMP(it0 + 30, Ar01, Ar23, Ai01, Ai23);
            W0; COMP(it0 + 31, Br01, Br23, Bi01, Bi23);
            asm volatile("s_waitcnt lgkmcnt(0)" ::: "memory");     // z writes sealed
            __builtin_amdgcn_s_barrier();                          // #3..#18
        }

        if (lane < 32) {
            r_f[gch] = r;
            phi_f[gch] = (float)((double)p0
                         + (double)a_rev * 2048.0 * 6.283185307179586476925287
                         + (double)acc);
        }
    }
}

extern "C" void kernel_launch(void* const* d_in, const int* in_sizes, int n_in,
                              void* d_out, int out_size, void* d_ws, size_t ws_size,
                              hipStream_t stream) {
    const float* Xr   = (const float*)d_in[0];
    const float* Xi   = (const float*)d_in[1];
    const float* r0   = (const float*)d_in[2];
    const float* phi0 = (const float*)d_in[3];
    const float* om   = (const float*)d_in[4];

    float* out   = (float*)d_out;
    float* zrp   = out;                               // Re(z): T*NCH floats
    float* r_f   = out + (size_t)2048 * NCH;          // NCH floats
    float* phi_f = r_f + NCH;                         // NCH floats

    reshopf_kernel<<<NBLK, 320, 0, stream>>>(Xr, Xi, r0, phi0, om, zrp, r_f, phi_f);
}